// Round 9
// baseline (297.373 us; speedup 1.0000x reference)
//
#include <hip/hip_runtime.h>
#include <stdint.h>

#define D_EMB 128
#define HIDDEN 64
#define PACK_SCALE 1024.0f
#define INV_PACK (1.0f/1024.0f)
#define PN 32        // nodes per proj block
#define LOG_SZ 21    // hash slots = 2^21 (16 MB), load factor ~0.3

__device__ __forceinline__ uint32_t rotl32(uint32_t x, int r) {
    return (x << r) | (x >> (32 - r));
}

// Bit-exact JAX threefry2x32, PARTITIONABLE path (default since jax 0.4.36).
// key = jax.random.key(42) -> (k1,k2) = (0,42); draw = final_x0 ^ final_x1 of
// counts (0, e).
__device__ __forceinline__ uint32_t jax_threefry_bits_part(uint32_t e) {
    const uint32_t ks0 = 0u;
    const uint32_t ks1 = 42u;
    const uint32_t ks2 = 0x1BD11BDAu ^ 0u ^ 42u;
    uint32_t x0 = 0u + ks0;
    uint32_t x1 = e + ks1;
#define TF_R(r) { x0 += x1; x1 = rotl32(x1, (r)); x1 ^= x0; }
    TF_R(13) TF_R(15) TF_R(26) TF_R(6)
    x0 += ks1; x1 += ks2 + 1u;
    TF_R(17) TF_R(29) TF_R(16) TF_R(24)
    x0 += ks2; x1 += ks0 + 2u;
    TF_R(13) TF_R(15) TF_R(26) TF_R(6)
    x0 += ks0; x1 += ks1 + 3u;
    TF_R(17) TF_R(29) TF_R(16) TF_R(24)
    x0 += ks1; x1 += ks2 + 4u;
    TF_R(13) TF_R(15) TF_R(26) TF_R(6)
    x0 += ks2; x1 += ks0 + 5u;
#undef TF_R
    return x0 ^ x1;
}

// Per-edge MLP logit -> concrete-sample gate value v in (0,1).
__device__ __forceinline__ float edge_gate_value(
    const float* __restrict__ Pcat, const float* __restrict__ w2s, float b2v,
    int c, int r, int e) {
    const float4* p1 = (const float4*)(Pcat + (size_t)c * (2 * HIDDEN));
    const float4* p2 = (const float4*)(Pcat + (size_t)r * (2 * HIDDEN) + HIDDEN);
    const float4* w4 = (const float4*)w2s;
    float la = b2v;
#pragma unroll
    for (int k = 0; k < HIDDEN / 4; k++) {
        float4 a = p1[k];
        float4 b = p2[k];
        float4 w = w4[k];
        la += fmaxf(a.x + b.x, 0.0f) * w.x + fmaxf(a.y + b.y, 0.0f) * w.y +
              fmaxf(a.z + b.z, 0.0f) * w.z + fmaxf(a.w + b.w, 0.0f) * w.w;
    }
    uint32_t bits = jax_threefry_bits_part((uint32_t)e);
    float u = __uint_as_float((bits >> 9) | 0x3f800000u) - 1.0f;
    // sigmoid(log(u) - log1p(-u) + la) == u / (u + (1-u)*exp(-la))
    return u / (u + (1.0f - u) * __expf(-la));
}

// Kernel 1 (proj v3): thread owns one output column, register-tiles 16 nodes.
// Pcat[n][0:64] = embed[n] @ W1[:128] + b1 ; Pcat[n][64:128] = embed[n] @ W1[128:]
__global__ __launch_bounds__(256) void node_proj_kernel(
    const float* __restrict__ embed, const float* __restrict__ W1,
    const float* __restrict__ b1, float* __restrict__ Pcat, int N) {
    __shared__ float e_lds[PN][D_EMB];    // 16 KB
    int n0 = blockIdx.x * PN;
    int t = threadIdx.x;
    {
        const float4* src = (const float4*)embed + (size_t)n0 * (D_EMB / 4);
        float4* dst = (float4*)&e_lds[0][0];
        for (int i = t; i < PN * (D_EMB / 4); i += 256) {
            int node = n0 + (i >> 5);
            float4 v = make_float4(0.f, 0.f, 0.f, 0.f);
            if (node < N) v = src[i];
            dst[i] = v;
        }
    }
    __syncthreads();
    int col = t & 127;
    int nset = t >> 7;
    int half = col >> 6, k = col & 63;
    const float* w = W1 + (size_t)half * D_EMB * HIDDEN + k;
    float bias = (half == 0) ? b1[k] : 0.0f;
    float acc[16];
#pragma unroll
    for (int j = 0; j < 16; j++) acc[j] = bias;
    const int nb = nset * 16;
#pragma unroll 8
    for (int d = 0; d < D_EMB; d++) {
        float wd = w[(size_t)d * HIDDEN];
#pragma unroll
        for (int j = 0; j < 16; j++) acc[j] += e_lds[nb + j][d] * wd;
    }
#pragma unroll
    for (int j = 0; j < 16; j++) {
        int node = n0 + nb + j;
        if (node < N) Pcat[(size_t)node * (2 * HIDDEN) + col] = acc[j];
    }
}

// Kernel 2 (hash path): per-edge gate -> hash accumulate + bitmap mark.
// Slot 2h = key+1 (0 empty), slot 2h+1 = float bits of 1024*cnt + sum(v).
__global__ __launch_bounds__(256) void scatter_hash_kernel(
    const int* __restrict__ ei, const float* __restrict__ Pcat,
    const float* __restrict__ W2, const float* __restrict__ b2,
    uint32_t* __restrict__ tab, uint32_t* __restrict__ bitmap, int E, int N) {
    __shared__ float w2s[HIDDEN];
    if (threadIdx.x < HIDDEN) w2s[threadIdx.x] = W2[threadIdx.x];
    __syncthreads();
    int e = blockIdx.x * blockDim.x + threadIdx.x;
    if (e >= E) return;
    int c = ei[e];
    int r = ei[E + e];
    if ((unsigned)c >= (unsigned)N || (unsigned)r >= (unsigned)N) return;

    float v = edge_gate_value(Pcat, w2s, b2[0], c, r, e);

    uint32_t key = (uint32_t)c * (uint32_t)N + (uint32_t)r;
    atomicOr(&bitmap[key >> 5], 1u << (key & 31));

    const uint32_t mask = (1u << LOG_SZ) - 1u;
    uint32_t h = (key * 2654435761u) >> (32 - LOG_SZ);
    for (;;) {
        uint32_t prev = atomicCAS(&tab[2 * h], 0u, key + 1u);
        if (prev == 0u || prev == key + 1u) break;
        h = (h + 1u) & mask;
    }
    atomicAdd((float*)&tab[2 * h + 1], PACK_SCALE + v);
}

__device__ __forceinline__ float hash_lookup(
    const uint32_t* __restrict__ tab, uint32_t key) {
    const uint32_t mask = (1u << LOG_SZ) - 1u;
    uint32_t h = (key * 2654435761u) >> (32 - LOG_SZ);
    for (;;) {
        uint2 ent = ((const uint2*)tab)[h];
        if (ent.x == key + 1u) return __uint_as_float(ent.y);
        if (ent.x == 0u) return 0.0f;
        h = (h + 1u) & mask;
    }
}

// Kernel 3: dense writer. Every cell written exactly once (no prior memset
// needed; prior buffer state irrelevant -> replay-safe). One float4 per
// thread, lane-contiguous (1KB/wave/instruction = full-BW pattern).
__global__ __launch_bounds__(256) void dense_write_kernel(
    const uint32_t* __restrict__ tab, const uint32_t* __restrict__ bitmap,
    float4* __restrict__ out4, size_t n4, int N) {
    size_t q = (size_t)blockIdx.x * 256 + threadIdx.x;
    if (q >= n4) return;
    uint32_t nib = (bitmap[q >> 3] >> ((q & 7) * 4)) & 0xFu;
    float4 res = make_float4(0.f, 0.f, 0.f, 0.f);
    if (nib) {
        float* rp = (float*)&res;
#pragma unroll
        for (int j = 0; j < 4; j++) {
            if (nib & (1u << j)) {
                uint32_t cell = (uint32_t)(q * 4 + j);
                uint32_t c = cell / (uint32_t)N;
                uint32_t r = cell - c * (uint32_t)N;
                float a = hash_lookup(tab, cell);                      // own (exists)
                float m = hash_lookup(tab, r * (uint32_t)N + c);       // mirror (maybe 0)
                float cnt_a = truncf(a * INV_PACK);
                float s_a = a - PACK_SCALE * cnt_a;
                float cnt_m = truncf(m * INV_PACK);
                float s_m = m - PACK_SCALE * cnt_m;
                rp[j] = cnt_a * 0.5f * (s_a + s_m);
            }
        }
    }
    out4[q] = res;
}

// ---------------- fallback path (ws too small): R8 proven pipeline ----------------

__global__ __launch_bounds__(256) void edge_scatter_kernel(
    const int* __restrict__ ei, const float* __restrict__ Pcat,
    const float* __restrict__ W2, const float* __restrict__ b2,
    float* __restrict__ out, int E, int N) {
    __shared__ float w2s[HIDDEN];
    if (threadIdx.x < HIDDEN) w2s[threadIdx.x] = W2[threadIdx.x];
    __syncthreads();
    int e = blockIdx.x * blockDim.x + threadIdx.x;
    if (e >= E) return;
    int c = ei[e];
    int r = ei[E + e];
    if ((unsigned)c >= (unsigned)N || (unsigned)r >= (unsigned)N) return;
    float v = edge_gate_value(Pcat, w2s, b2[0], c, r, e);
    atomicAdd(out + (size_t)c * N + r, PACK_SCALE + v);
}

__global__ __launch_bounds__(256) void edge_finalize_kernel(
    const int* __restrict__ ei, float* __restrict__ out, int E, int N) {
    int e = blockIdx.x * blockDim.x + threadIdx.x;
    if (e >= E) return;
    int c = ei[e];
    int r = ei[E + e];
    if ((unsigned)c >= (unsigned)N || (unsigned)r >= (unsigned)N) return;
    size_t own = (size_t)c * N + r;
    size_t mir = (size_t)r * N + c;
    float a = out[own];
    if (a < PACK_SCALE) return;
    float b = out[mir];
    if (c != r && b > 0.0f && b < PACK_SCALE) return;
    if (c <= r || b == 0.0f) {
        float cnt_a = truncf(a * INV_PACK);
        float s_a = a - PACK_SCALE * cnt_a;
        float cnt_b = truncf(b * INV_PACK);
        float s_b = b - PACK_SCALE * cnt_b;
        float sum = s_a + s_b;
        out[own] = cnt_a * 0.5f * sum;
        if (c < r && b != 0.0f) out[mir] = cnt_b * 0.5f * sum;
    }
}

extern "C" void kernel_launch(void* const* d_in, const int* in_sizes, int n_in,
                              void* d_out, int out_size, void* d_ws, size_t ws_size,
                              hipStream_t stream) {
    const float* embed = (const float*)d_in[0];
    const int*   ei    = (const int*)d_in[1];
    const float* W1    = (const float*)d_in[2];
    const float* b1    = (const float*)d_in[3];
    const float* W2    = (const float*)d_in[4];
    const float* b2    = (const float*)d_in[5];
    float* out = (float*)d_out;

    const int N = in_sizes[0] / D_EMB;      // 10000
    const int E = in_sizes[1] / 2;          // 640000

    float* Pcat = (float*)d_ws;             // N*128 floats = 5.12 MB
    size_t pcat_bytes = ((size_t)N * 2 * HIDDEN * sizeof(float) + 255) & ~(size_t)255;
    size_t tab_bytes = (size_t)8 << LOG_SZ;                      // 16 MB
    size_t bitmap_bytes = (((size_t)N * N + 31) / 32) * 4;       // 12.5 MB
    size_t need = pcat_bytes + tab_bytes + bitmap_bytes;

    const int eb = 256;
    const int eg = (E + eb - 1) / eb;

    node_proj_kernel<<<(N + PN - 1) / PN, 256, 0, stream>>>(embed, W1, b1, Pcat, N);

    if (ws_size >= need) {
        uint32_t* tab = (uint32_t*)((char*)d_ws + pcat_bytes);
        uint32_t* bitmap = (uint32_t*)((char*)d_ws + pcat_bytes + tab_bytes);
        // zero hash + bitmap (contiguous, ~28.5 MB ≈ 6 µs) — NOT the 400 MB out
        hipMemsetAsync(tab, 0, tab_bytes + bitmap_bytes, stream);
        scatter_hash_kernel<<<eg, eb, 0, stream>>>(ei, Pcat, W2, b2, tab, bitmap, E, N);
        size_t n4 = (size_t)out_size / 4;
        uint32_t wblocks = (uint32_t)((n4 + 255) / 256);
        dense_write_kernel<<<wblocks, 256, 0, stream>>>(tab, bitmap, (float4*)out, n4, N);
    } else {
        // proven R8 path
        hipMemsetAsync(d_out, 0, (size_t)out_size * sizeof(float), stream);
        edge_scatter_kernel<<<eg, eb, 0, stream>>>(ei, Pcat, W2, b2, out, E, N);
        edge_finalize_kernel<<<eg, eb, 0, stream>>>(ei, out, E, N);
    }
}

// Round 10
// 221.174 us; speedup vs baseline: 1.3445x; 1.3445x over previous
//
#include <hip/hip_runtime.h>
#include <stdint.h>

#define D_EMB 128
#define HIDDEN 64
#define PACK_SCALE 1024.0f
#define INV_PACK (1.0f/1024.0f)
#define PN 32   // nodes per proj block

__device__ __forceinline__ uint32_t rotl32(uint32_t x, int r) {
    return (x << r) | (x >> (32 - r));
}

// Bit-exact JAX threefry2x32, PARTITIONABLE path (default since jax 0.4.36).
// key = jax.random.key(42) -> (k1,k2) = (0,42); draw = final_x0 ^ final_x1 of
// counts (0, e).
__device__ __forceinline__ uint32_t jax_threefry_bits_part(uint32_t e) {
    const uint32_t ks0 = 0u;
    const uint32_t ks1 = 42u;
    const uint32_t ks2 = 0x1BD11BDAu ^ 0u ^ 42u;
    uint32_t x0 = 0u + ks0;
    uint32_t x1 = e + ks1;
#define TF_R(r) { x0 += x1; x1 = rotl32(x1, (r)); x1 ^= x0; }
    TF_R(13) TF_R(15) TF_R(26) TF_R(6)
    x0 += ks1; x1 += ks2 + 1u;
    TF_R(17) TF_R(29) TF_R(16) TF_R(24)
    x0 += ks2; x1 += ks0 + 2u;
    TF_R(13) TF_R(15) TF_R(26) TF_R(6)
    x0 += ks0; x1 += ks1 + 3u;
    TF_R(17) TF_R(29) TF_R(16) TF_R(24)
    x0 += ks1; x1 += ks2 + 4u;
    TF_R(13) TF_R(15) TF_R(26) TF_R(6)
    x0 += ks2; x1 += ks0 + 5u;
#undef TF_R
    return x0 ^ x1;
}

// Per-edge MLP logit -> concrete-sample gate value v in (0,1).
__device__ __forceinline__ float edge_gate_value(
    const float* __restrict__ Pcat, const float* __restrict__ w2s, float b2v,
    int c, int r, int e) {
    const float4* p1 = (const float4*)(Pcat + (size_t)c * (2 * HIDDEN));
    const float4* p2 = (const float4*)(Pcat + (size_t)r * (2 * HIDDEN) + HIDDEN);
    const float4* w4 = (const float4*)w2s;
    float la = b2v;
#pragma unroll
    for (int k = 0; k < HIDDEN / 4; k++) {
        float4 a = p1[k];
        float4 b = p2[k];
        float4 w = w4[k];
        la += fmaxf(a.x + b.x, 0.0f) * w.x + fmaxf(a.y + b.y, 0.0f) * w.y +
              fmaxf(a.z + b.z, 0.0f) * w.z + fmaxf(a.w + b.w, 0.0f) * w.w;
    }
    uint32_t bits = jax_threefry_bits_part((uint32_t)e);
    float u = __uint_as_float((bits >> 9) | 0x3f800000u) - 1.0f;
    // sigmoid(log(u) - log1p(-u) + la) == u / (u + (1-u)*exp(-la))
    return u / (u + (1.0f - u) * __expf(-la));
}

// Kernel 1 (proj v3): thread owns one output column, register-tiles 16 nodes,
// so each W1 element is fetched once per 16 nodes (W1 L2 traffic 640->80 MB).
// Pcat[n][0:64] = embed[n] @ W1[:128] + b1 ; Pcat[n][64:128] = embed[n] @ W1[128:]
__global__ __launch_bounds__(256) void node_proj_kernel(
    const float* __restrict__ embed, const float* __restrict__ W1,
    const float* __restrict__ b1, float* __restrict__ Pcat, int N) {
    __shared__ float e_lds[PN][D_EMB];    // 16 KB
    int n0 = blockIdx.x * PN;
    int t = threadIdx.x;
    {   // cooperative load: PN*32 = 1024 float4s, 4 per thread
        const float4* src = (const float4*)embed + (size_t)n0 * (D_EMB / 4);
        float4* dst = (float4*)&e_lds[0][0];
        for (int i = t; i < PN * (D_EMB / 4); i += 256) {
            int node = n0 + (i >> 5);
            float4 v = make_float4(0.f, 0.f, 0.f, 0.f);
            if (node < N) v = src[i];
            dst[i] = v;
        }
    }
    __syncthreads();
    int col = t & 127;
    int nset = t >> 7;                    // 0/1 -> nodes nset*16 .. +15
    int half = col >> 6, k = col & 63;
    const float* w = W1 + (size_t)half * D_EMB * HIDDEN + k;
    float bias = (half == 0) ? b1[k] : 0.0f;
    float acc[16];
#pragma unroll
    for (int j = 0; j < 16; j++) acc[j] = bias;
    const int nb = nset * 16;
#pragma unroll 8
    for (int d = 0; d < D_EMB; d++) {
        float wd = w[(size_t)d * HIDDEN];
#pragma unroll
        for (int j = 0; j < 16; j++) acc[j] += e_lds[nb + j][d] * wd;  // LDS broadcast
    }
#pragma unroll
    for (int j = 0; j < 16; j++) {
        int node = n0 + nb + j;
        if (node < N) Pcat[(size_t)node * (2 * HIDDEN) + col] = acc[j];
    }
}

// Kernel 2: per-edge gate value, packed atomic accumulate into out[c*N+r].
// Cell state after this pass: 1024*cnt + sum(v), always >= 1024 for touched.
__global__ __launch_bounds__(256) void edge_scatter_kernel(
    const int* __restrict__ ei, const float* __restrict__ Pcat,
    const float* __restrict__ W2, const float* __restrict__ b2,
    float* __restrict__ out, int E, int N) {
    __shared__ float w2s[HIDDEN];
    if (threadIdx.x < HIDDEN) w2s[threadIdx.x] = W2[threadIdx.x];
    __syncthreads();
    int e = blockIdx.x * blockDim.x + threadIdx.x;
    if (e >= E) return;
    int c = ei[e];
    int r = ei[E + e];
    if ((unsigned)c >= (unsigned)N || (unsigned)r >= (unsigned)N) return;
    float v = edge_gate_value(Pcat, w2s, b2[0], c, r, e);
    atomicAdd(out + (size_t)c * N + r, PACK_SCALE + v);
}

// Kernel 3a: per-edge read both packed cells, compute final value.
__global__ __launch_bounds__(256) void edge_read_kernel(
    const int* __restrict__ ei, const float* __restrict__ out,
    float* __restrict__ vals, int E, int N) {
    int e = blockIdx.x * blockDim.x + threadIdx.x;
    if (e >= E) return;
    int c = ei[e];
    int r = ei[E + e];
    if ((unsigned)c >= (unsigned)N || (unsigned)r >= (unsigned)N) return;
    float a = out[(size_t)c * N + r];
    float b = out[(size_t)r * N + c];
    float cnt_a = truncf(a * INV_PACK);
    float s_a = a - PACK_SCALE * cnt_a;
    float cnt_b = truncf(b * INV_PACK);
    float s_b = b - PACK_SCALE * cnt_b;
    vals[e] = cnt_a * 0.5f * (s_a + s_b);
}

// Kernel 3b: per-edge write final value (idempotent across duplicates).
__global__ __launch_bounds__(256) void edge_write_kernel(
    const int* __restrict__ ei, const float* __restrict__ vals,
    float* __restrict__ out, int E, int N) {
    int e = blockIdx.x * blockDim.x + threadIdx.x;
    if (e >= E) return;
    int c = ei[e];
    int r = ei[E + e];
    if ((unsigned)c >= (unsigned)N || (unsigned)r >= (unsigned)N) return;
    out[(size_t)c * N + r] = vals[e];
}

extern "C" void kernel_launch(void* const* d_in, const int* in_sizes, int n_in,
                              void* d_out, int out_size, void* d_ws, size_t ws_size,
                              hipStream_t stream) {
    const float* embed = (const float*)d_in[0];
    const int*   ei    = (const int*)d_in[1];
    const float* W1    = (const float*)d_in[2];
    const float* b1    = (const float*)d_in[3];
    const float* W2    = (const float*)d_in[4];
    const float* b2    = (const float*)d_in[5];
    float* out = (float*)d_out;

    const int N = in_sizes[0] / D_EMB;      // 10000
    const int E = in_sizes[1] / 2;          // 640000

    float* Pcat = (float*)d_ws;             // N*128 floats = 5.12 MB
    size_t pcat_bytes = ((size_t)N * 2 * HIDDEN * sizeof(float) + 255) & ~(size_t)255;
    float* vals = (float*)((char*)d_ws + pcat_bytes);  // E floats

    // Zero the dense output. Best measured full-write of out: the memset node
    // (~102us; out-buffer writes cap ~4TB/s for ALL writers: rocclr fill,
    // grid-stride kernel (R3, 125us), striped-nt (R7, 510us), dense sweep (R9)).
    hipMemsetAsync(d_out, 0, (size_t)out_size * sizeof(float), stream);

    node_proj_kernel<<<(N + PN - 1) / PN, 256, 0, stream>>>(embed, W1, b1, Pcat, N);

    const int eb = 256;
    const int eg = (E + eb - 1) / eb;
    edge_scatter_kernel<<<eg, eb, 0, stream>>>(ei, Pcat, W2, b2, out, E, N);
    edge_read_kernel<<<eg, eb, 0, stream>>>(ei, out, vals, E, N);
    edge_write_kernel<<<eg, eb, 0, stream>>>(ei, vals, out, E, N);
}